// Round 1
// baseline (313.771 us; speedup 1.0000x reference)
//
#include <hip/hip_runtime.h>
#include <stdint.h>

typedef unsigned short u16;
typedef __bf16 bf16x8 __attribute__((ext_vector_type(8)));
typedef u16 u16x8 __attribute__((ext_vector_type(8)));
typedef float f32x4 __attribute__((ext_vector_type(4)));

#define MFMA16(a,b,c) __builtin_amdgcn_mfma_f32_16x16x32_bf16((a),(b),(c),0,0,0)
#define GLOAD16(gp, lp) __builtin_amdgcn_global_load_lds( \
    (const __attribute__((address_space(1))) void*)(gp), \
    (__attribute__((address_space(3))) void*)(lp), 16, 0, 0)

__device__ __forceinline__ u16 f2bf(float f) {
  union { float f; uint32_t u; } v; v.f = f;
  return (u16)((v.u + 0x7FFFu + ((v.u >> 16) & 1u)) >> 16);
}
__device__ __forceinline__ float bits2f(uint32_t u) {
  union { uint32_t u; float f; } v; v.u = u; return v.f;
}

// ---------------- fp32 -> bf16 convert (float4 vectorized) ----------------
__global__ void k_cvt(const float* __restrict__ in, u16* __restrict__ out, int n4) {
  int i = blockIdx.x * 256 + threadIdx.x;
  int stride = gridDim.x * 256;
  for (; i < n4; i += stride) {
    float4 v = reinterpret_cast<const float4*>(in)[i];
    ushort4 o;
    o.x = f2bf(v.x); o.y = f2bf(v.y); o.z = f2bf(v.z); o.w = f2bf(v.w);
    reinterpret_cast<ushort4*>(out)[i] = o;
  }
}

// ------------- fp32 (R x C) -> bf16 transposed (C x R), 32x32 tiles -------------
__global__ void k_transpose(const float* __restrict__ in, u16* __restrict__ out, int R, int C) {
  __shared__ float t[32][33];
  int tx = threadIdx.x & 31, ty = threadIdx.x >> 5;
  int c0 = blockIdx.x * 32, r0 = blockIdx.y * 32;
  #pragma unroll
  for (int i = 0; i < 4; i++)
    t[ty + i*8][tx] = in[(size_t)(r0 + ty + i*8) * C + (c0 + tx)];
  __syncthreads();
  #pragma unroll
  for (int i = 0; i < 4; i++)
    out[(size_t)(c0 + ty + i*8) * R + (r0 + tx)] = f2bf(t[tx][ty + i*8]);
}

// ---------------- 128x128 bf16 GEMM core (m97 structure + slot swizzle) ----------------
// A: (M x K) bf16 row-major.  BT: (N x K) bf16 row-major (i.e. B^T).
// 256 threads = 4 waves, each wave a 64x64 quadrant = 4x4 frags of 16x16x32 MFMA, BK=32.
// Staging via global_load_lds(16B) with source slot-swizzle (slot ^= (row>>1)&3)
// so ds_read_b128 fragment reads are 2-way (free) instead of 8-way bank conflicted.
template<int KDIM>
__device__ __forceinline__ void gemm_core(
    const u16* __restrict__ A, const u16* __restrict__ BT,
    int mt, int nt, f32x4 acc[4][4], u16* As, u16* Bs)
{
  int tid = threadIdx.x, lane = tid & 63, w = tid >> 6;
  int g = lane >> 4, c4 = lane & 15;
  int wr = w >> 1, wc = w & 1;
  int srow = lane >> 2;                          // row within 16-row chunk
  int pslot = (lane & 3) ^ ((lane >> 3) & 3);    // swizzled source slot
  int rsel = g ^ ((c4 >> 1) & 3);                // swizzled read slot
  const size_t abase = (size_t)(mt * 128) * KDIM;
  const size_t bbase = (size_t)(nt * 128) * KDIM;
  for (int kt = 0; kt < KDIM / 32; kt++) {
    __syncthreads();
    #pragma unroll
    for (int cc = 0; cc < 2; cc++) {
      int cid = w * 2 + cc;                      // 8 x 1KB chunks each for A,B
      int row = cid * 16 + srow;
      GLOAD16(A + abase + (size_t)row * KDIM + kt * 32 + pslot * 8, As + cid * 512);
      GLOAD16(BT + bbase + (size_t)row * KDIM + kt * 32 + pslot * 8, Bs + cid * 512);
    }
    __syncthreads();
    bf16x8 af[4], bfv[4];
    #pragma unroll
    for (int f = 0; f < 4; f++) {
      af[f]  = *(const bf16x8*)(As + (wr * 64 + f * 16 + c4) * 32 + rsel * 8);
      bfv[f] = *(const bf16x8*)(Bs + (wc * 64 + f * 16 + c4) * 32 + rsel * 8);
    }
    #pragma unroll
    for (int fr = 0; fr < 4; fr++)
      #pragma unroll
      for (int fc = 0; fc < 4; fc++)
        acc[fr][fc] = MFMA16(af[fr], bfv[fc], acc[fr][fc]);
  }
}

// ---------------- K1: QKV projection GEMM ----------------
// C(25088 x 2304) = xb @ qkv_w + b, written as bf16 q/k/v in (head*128+b, l, 64) layout.
__global__ __launch_bounds__(256, 3) void k_qkv_gemm(
    const u16* __restrict__ A, const u16* __restrict__ BT, const float* __restrict__ bias,
    u16* __restrict__ qo, u16* __restrict__ ko, u16* __restrict__ vo)
{
  __shared__ u16 As[128 * 32], Bs[128 * 32];
  int bid = blockIdx.x;
  int nt = bid % 18, mt = bid / 18;
  f32x4 z = {0.f, 0.f, 0.f, 0.f};
  f32x4 acc[4][4];
  #pragma unroll
  for (int i = 0; i < 4; i++)
    #pragma unroll
    for (int j = 0; j < 4; j++) acc[i][j] = z;
  gemm_core<768>(A, BT, mt, nt, acc, As, Bs);

  int tid = threadIdx.x, lane = tid & 63, w = tid >> 6;
  int g = lane >> 4, c4 = lane & 15;
  int wr = w >> 1, wc = w & 1;

  u16* dstA[4]; int ccA[4]; float bsA[4]; int hbA[4];
  #pragma unroll
  for (int fc = 0; fc < 4; fc++) {
    int n0 = nt * 128 + wc * 64 + fc * 16;       // 16-aligned, tile within one of {q,k,v}
    int i3 = n0 / 768;
    int r = n0 - i3 * 768;
    dstA[fc] = (i3 == 0) ? qo : (i3 == 1) ? ko : vo;
    hbA[fc] = (r >> 6) * 128;                    // head*128
    ccA[fc] = (r & 63) + c4;                     // channel
    bsA[fc] = bias[n0 + c4];
  }
  #pragma unroll
  for (int fr = 0; fr < 4; fr++) {
    #pragma unroll
    for (int j = 0; j < 4; j++) {
      int m = mt * 128 + wr * 64 + fr * 16 + g * 4 + j;
      int bb = m / 196;
      int ll = m - bb * 196;
      #pragma unroll
      for (int fc = 0; fc < 4; fc++) {
        dstA[fc][(size_t)((hbA[fc] + bb) * 196 + ll) * 64 + ccA[fc]] =
            f2bf(acc[fr][fc][j] + bsA[fc]);
      }
    }
  }
}

// ---------------- K3: output projection GEMM ----------------
__global__ __launch_bounds__(256, 3) void k_proj_gemm(
    const u16* __restrict__ A, const u16* __restrict__ BT, const float* __restrict__ bias,
    float* __restrict__ out)
{
  __shared__ u16 As[128 * 32], Bs[128 * 32];
  int bid = blockIdx.x;
  int nt = bid % 6, mt = bid / 6;
  f32x4 z = {0.f, 0.f, 0.f, 0.f};
  f32x4 acc[4][4];
  #pragma unroll
  for (int i = 0; i < 4; i++)
    #pragma unroll
    for (int j = 0; j < 4; j++) acc[i][j] = z;
  gemm_core<768>(A, BT, mt, nt, acc, As, Bs);

  int tid = threadIdx.x, lane = tid & 63, w = tid >> 6;
  int g = lane >> 4, c4 = lane & 15;
  int wr = w >> 1, wc = w & 1;
  #pragma unroll
  for (int fc = 0; fc < 4; fc++) {
    int n0 = nt * 128 + wc * 64 + fc * 16 + c4;
    float bs = bias[n0];
    #pragma unroll
    for (int fr = 0; fr < 4; fr++)
      #pragma unroll
      for (int j = 0; j < 4; j++) {
        int m = mt * 128 + wr * 64 + fr * 16 + g * 4 + j;
        out[(size_t)m * 768 + n0] = acc[fr][fc][j] + bs;
      }
  }
}

// ---------------- K2: fused attention ----------------
// One block (4 waves) per (head, batch). L=196 padded to 208 (13 q-tiles of 16).
// K in LDS [208][72] (pad-72 -> 2-way banks), V transposed to [64][216], per-wave
// P buffer [16][136]. Rel-pos: E = Q_tile @ relpos^T via MFMA, gathered into S with
// packed-bf16 ds_bpermute (E row == S row lives in same 16-lane group).
// Online softmax over 2 key chunks (112 + 96) so P LDS stays small.
#define KP 72
#define VP 216
#define PP 136

template<int NT, int KT0, int NMF, int KOFS>
__device__ __forceinline__ void attn_chunk(
    const u16* Kl, const u16* VT, u16* Pw,
    bf16x8 qa0, bf16x8 qa1,
    const uint32_t* ph, const uint32_t* pw,
    const int* qh, const int* qw,
    float* m_run, float* l_run, f32x4* O,
    int g, int c4, int lane)
{
  f32x4 z = {0.f, 0.f, 0.f, 0.f};
  f32x4 S[NT];
  #pragma unroll
  for (int i = 0; i < NT; i++) {
    int key = (KT0 + i) * 16 + c4;
    bf16x8 kb0 = *(const bf16x8*)(Kl + key * KP + g * 8);
    bf16x8 kb1 = *(const bf16x8*)(Kl + key * KP + 32 + g * 8);
    S[i] = MFMA16(qa1, kb1, MFMA16(qa0, kb0, z));
  }
  // scale + rel-pos gather + mask
  #pragma unroll
  for (int i = 0; i < NT; i++) {
    int kglob = (KT0 + i) * 16 + c4;
    int kh = kglob / 14;
    int kw = kglob - kh * 14;
    bool valid = (kglob < 196);
    #pragma unroll
    for (int j = 0; j < 4; j++) {
      int ih = qh[j] - kh + 13;
      int iw = qw[j] - kw + 13;
      uint32_t vh = (uint32_t)__builtin_amdgcn_ds_bpermute(((lane & 48) | (ih & 15)) << 2, (int)ph[j]);
      uint32_t vw = (uint32_t)__builtin_amdgcn_ds_bpermute(((lane & 48) | (iw & 15)) << 2, (int)pw[j]);
      float eh = bits2f((ih >= 16) ? (vh & 0xFFFF0000u) : (vh << 16));
      float ew = bits2f((iw >= 16) ? (vw & 0xFFFF0000u) : (vw << 16));
      float s = S[i][j] * 0.125f + eh + ew;
      S[i][j] = valid ? s : -1e30f;
    }
  }
  // online-softmax update (rows live in 16-lane groups; reduce over lane bits 0..3)
  #pragma unroll
  for (int j = 0; j < 4; j++) {
    float t = S[0][j];
    #pragma unroll
    for (int i = 1; i < NT; i++) t = fmaxf(t, S[i][j]);
    t = fmaxf(t, __shfl_xor(t, 1));
    t = fmaxf(t, __shfl_xor(t, 2));
    t = fmaxf(t, __shfl_xor(t, 4));
    t = fmaxf(t, __shfl_xor(t, 8));
    float mn = fmaxf(m_run[j], t);
    float corr = __expf(m_run[j] - mn);
    m_run[j] = mn;
    l_run[j] *= corr;
    #pragma unroll
    for (int ct = 0; ct < 4; ct++) O[ct][j] *= corr;
  }
  // P = exp(S - m), write bf16 to per-wave LDS, accumulate row sums
  #pragma unroll
  for (int j = 0; j < 4; j++) {
    int prow = (g * 4 + j) * PP;
    float rs = 0.f;
    #pragma unroll
    for (int i = 0; i < NT; i++) {
      float p = __expf(S[i][j] - m_run[j]);
      rs += p;
      Pw[prow + i * 16 + c4] = f2bf(p);
    }
    if (NT == 7) Pw[prow + 112 + c4] = 0;   // zero pad tile so 4th PV MFMA is safe
    rs += __shfl_xor(rs, 1);
    rs += __shfl_xor(rs, 2);
    rs += __shfl_xor(rs, 4);
    rs += __shfl_xor(rs, 8);
    l_run[j] += rs;
  }
  // PV: O += P @ V  (A-frag from P, B-frag from VT)
  #pragma unroll
  for (int km = 0; km < NMF; km++) {
    bf16x8 pa = *(const bf16x8*)(Pw + c4 * PP + km * 32 + g * 8);
    #pragma unroll
    for (int ct = 0; ct < 4; ct++) {
      bf16x8 vb = *(const bf16x8*)(VT + (ct * 16 + c4) * VP + KOFS + km * 32 + g * 8);
      O[ct] = MFMA16(pa, vb, O[ct]);
    }
  }
}

__global__ __launch_bounds__(256, 2) void k_attn(
    const u16* __restrict__ Q, const u16* __restrict__ Kg, const u16* __restrict__ Vg,
    const u16* __restrict__ RPH, const u16* __restrict__ RPW, u16* __restrict__ Ows)
{
  __shared__ u16 sm[14976 + 13824 + 8704];   // K + VT + 4xP = 75008 B
  u16* Kl = sm;
  u16* VT = sm + 14976;
  u16* Pl = sm + 14976 + 13824;

  int bh = blockIdx.x;
  int hh = bh >> 7, bb = bh & 127;
  int tid = threadIdx.x, lane = tid & 63, w = tid >> 6;
  int g = lane >> 4, c4 = lane & 15;

  const u16* kbase = Kg + (size_t)bh * (196 * 64);
  const u16* vbase = Vg + (size_t)bh * (196 * 64);
  const u16* qbase = Q + (size_t)bh * (196 * 64);

  // stage K rows 0..195 (16B chunks), zero rows 196..207
  for (int ch = tid; ch < 1568; ch += 256) {
    int row = ch >> 3, slot = ch & 7;
    int4 val = *reinterpret_cast<const int4*>(kbase + row * 64 + slot * 8);
    *reinterpret_cast<int4*>(Kl + row * KP + slot * 8) = val;
  }
  for (int i2 = tid; i2 < 12 * KP; i2 += 256) Kl[196 * KP + i2] = 0;
  // stage V transposed: key-pairs packed as b32 writes
  for (int ch = tid; ch < 784; ch += 256) {
    int kp = ch >> 3, cb = ch & 7;
    int key = kp * 2, cz = cb * 8;
    u16x8 a = *(const u16x8*)(vbase + key * 64 + cz);
    u16x8 b2 = *(const u16x8*)(vbase + (key + 1) * 64 + cz);
    #pragma unroll
    for (int j = 0; j < 8; j++) {
      uint32_t pk = (uint32_t)a[j] | ((uint32_t)b2[j] << 16);
      *reinterpret_cast<uint32_t*>(VT + (cz + j) * VP + key) = pk;
    }
  }
  for (int i2 = tid; i2 < 64 * 20; i2 += 256) {
    int chn = i2 / 20, col = 196 + (i2 - chn * 20);
    VT[chn * VP + col] = 0;
  }
  __syncthreads();

  u16* Pw = Pl + w * (16 * PP);

  for (int qt = w; qt < 13; qt += 4) {
    int qrow = qt * 16 + c4; if (qrow > 195) qrow = 195;  // padded rows: clamp (unwritten later)
    const u16* qp = qbase + qrow * 64 + g * 8;
    bf16x8 qa0 = *(const bf16x8*)(qp);
    bf16x8 qa1 = *(const bf16x8*)(qp + 32);

    // E tables: E = Q_tile(16x64) @ relpos^T(64x32), cols = table index 0..26
    int t1 = 16 + c4; if (t1 > 26) t1 = 26;
    f32x4 z = {0.f, 0.f, 0.f, 0.f};
    f32x4 Eh0 = MFMA16(qa0, *(const bf16x8*)(RPH + c4 * 64 + g * 8), z);
    Eh0 = MFMA16(qa1, *(const bf16x8*)(RPH + c4 * 64 + 32 + g * 8), Eh0);
    f32x4 Eh1 = MFMA16(qa0, *(const bf16x8*)(RPH + t1 * 64 + g * 8), z);
    Eh1 = MFMA16(qa1, *(const bf16x8*)(RPH + t1 * 64 + 32 + g * 8), Eh1);
    f32x4 Ew0 = MFMA16(qa0, *(const bf16x8*)(RPW + c4 * 64 + g * 8), z);
    Ew0 = MFMA16(qa1, *(const bf16x8*)(RPW + c4 * 64 + 32 + g * 8), Ew0);
    f32x4 Ew1 = MFMA16(qa0, *(const bf16x8*)(RPW + t1 * 64 + g * 8), z);
    Ew1 = MFMA16(qa1, *(const bf16x8*)(RPW + t1 * 64 + 32 + g * 8), Ew1);

    uint32_t ph[4], pw[4];
    int qh[4], qw[4];
    #pragma unroll
    for (int j = 0; j < 4; j++) {
      ph[j] = (uint32_t)f2bf(Eh0[j]) | ((uint32_t)f2bf(Eh1[j]) << 16);
      pw[j] = (uint32_t)f2bf(Ew0[j]) | ((uint32_t)f2bf(Ew1[j]) << 16);
      int qi = qt * 16 + g * 4 + j;
      qh[j] = qi / 14;
      qw[j] = qi - qh[j] * 14;
    }

    float m_run[4] = {-3e38f, -3e38f, -3e38f, -3e38f};
    float l_run[4] = {0.f, 0.f, 0.f, 0.f};
    f32x4 O[4] = {z, z, z, z};

    attn_chunk<7, 0, 4, 0>(Kl, VT, Pw, qa0, qa1, ph, pw, qh, qw, m_run, l_run, O, g, c4, lane);
    attn_chunk<6, 7, 3, 112>(Kl, VT, Pw, qa0, qa1, ph, pw, qh, qw, m_run, l_run, O, g, c4, lane);

    #pragma unroll
    for (int j = 0; j < 4; j++) {
      int qi = qt * 16 + g * 4 + j;
      if (qi < 196) {
        float inv = 1.f / l_run[j];
        size_t base = (size_t)(bb * 196 + qi) * 768 + hh * 64;
        #pragma unroll
        for (int ct = 0; ct < 4; ct++)
          Ows[base + ct * 16 + c4] = f2bf(O[ct][j] * inv);
      }
    }
  }
}

// ---------------- host launch ----------------
extern "C" void kernel_launch(void* const* d_in, const int* in_sizes, int n_in,
                              void* d_out, int out_size, void* d_ws, size_t ws_size,
                              hipStream_t stream) {
  (void)in_sizes; (void)n_in; (void)out_size; (void)ws_size;
  const float* x      = (const float*)d_in[0];
  const float* qkv_w  = (const float*)d_in[1];
  const float* qkv_b  = (const float*)d_in[2];
  const float* proj_w = (const float*)d_in[3];
  const float* proj_b = (const float*)d_in[4];
  const float* rph    = (const float*)d_in[5];
  const float* rpw    = (const float*)d_in[6];
  float* out = (float*)d_out;
  char* ws = (char*)d_ws;

  // ws layout (bytes): xb/Ows share the first region (xb dead after K1)
  u16* xb   = (u16*)(ws);                 // 25088x768 bf16 = 38,535,168
  u16* wT   = (u16*)(ws + 38535168);      // 2304x768 bf16  =  3,538,944
  u16* pT   = (u16*)(ws + 42074112);      // 768x768 bf16   =  1,179,648
  u16* rphb = (u16*)(ws + 43253760);      // 27x64 bf16 (padded to 4096)
  u16* rpwb = (u16*)(ws + 43257856);      // 27x64 bf16
  u16* qws  = (u16*)(ws + 43261952);      // 1536x196x64 bf16 = 38,535,168
  u16* kws  = (u16*)(ws + 81797120);
  u16* vws  = (u16*)(ws + 120332288);     // end = 158,867,456
  u16* Ows  = xb;

  k_cvt<<<2048, 256, 0, stream>>>(x, xb, 4816896);
  k_cvt<<<2, 256, 0, stream>>>(rph, rphb, 432);
  k_cvt<<<2, 256, 0, stream>>>(rpw, rpwb, 432);
  k_transpose<<<dim3(72, 24), 256, 0, stream>>>(qkv_w, wT, 768, 2304);
  k_transpose<<<dim3(24, 24), 256, 0, stream>>>(proj_w, pT, 768, 768);
  k_qkv_gemm<<<196 * 18, 256, 0, stream>>>(xb, wT, qkv_b, qws, kws, vws);
  k_attn<<<1536, 256, 0, stream>>>(qws, kws, vws, rphb, rpwb, Ows);
  k_proj_gemm<<<196 * 6, 256, 0, stream>>>(Ows, pT, proj_b, out);
}

// Round 2
// 275.306 us; speedup vs baseline: 1.1397x; 1.1397x over previous
//
#include <hip/hip_runtime.h>
#include <stdint.h>

typedef unsigned short u16;
typedef __bf16 bf16x8 __attribute__((ext_vector_type(8)));
typedef u16 u16x8 __attribute__((ext_vector_type(8)));
typedef float f32x4 __attribute__((ext_vector_type(4)));

#define MFMA16(a,b,c) __builtin_amdgcn_mfma_f32_16x16x32_bf16((a),(b),(c),0,0,0)
#define GLOAD16(gp, lp) __builtin_amdgcn_global_load_lds( \
    (const __attribute__((address_space(1))) void*)(gp), \
    (__attribute__((address_space(3))) void*)(lp), 16, 0, 0)

__device__ __forceinline__ u16 f2bf(float f) {
  union { float f; uint32_t u; } v; v.f = f;
  return (u16)((v.u + 0x7FFFu + ((v.u >> 16) & 1u)) >> 16);
}
__device__ __forceinline__ float bits2f(uint32_t u) {
  union { uint32_t u; float f; } v; v.u = u; return v.f;
}
__device__ __forceinline__ uint32_t cvtpk(float lo, float hi) {
  uint32_t r;
  asm("v_cvt_pk_bf16_f32 %0, %1, %2" : "=v"(r) : "v"(lo), "v"(hi));
  return r;
}
__device__ __forceinline__ int4 pack8(const u16* v) {
  int4 r;
  r.x = (int)((uint32_t)v[0] | ((uint32_t)v[1] << 16));
  r.y = (int)((uint32_t)v[2] | ((uint32_t)v[3] << 16));
  r.z = (int)((uint32_t)v[4] | ((uint32_t)v[5] << 16));
  r.w = (int)((uint32_t)v[6] | ((uint32_t)v[7] << 16));
  return r;
}

// ---------------- fp32 -> bf16 convert ----------------
__global__ void k_cvt(const float* __restrict__ in, u16* __restrict__ out, int n4) {
  int i = blockIdx.x * 256 + threadIdx.x;
  int stride = gridDim.x * 256;
  for (; i < n4; i += stride) {
    float4 v = reinterpret_cast<const float4*>(in)[i];
    ushort4 o;
    o.x = f2bf(v.x); o.y = f2bf(v.y); o.z = f2bf(v.z); o.w = f2bf(v.w);
    reinterpret_cast<ushort4*>(out)[i] = o;
  }
}

// ------------- fp32 (R x C) -> bf16 transposed (C x R) -------------
__global__ void k_transpose(const float* __restrict__ in, u16* __restrict__ out, int R, int C) {
  __shared__ float t[32][33];
  int tx = threadIdx.x & 31, ty = threadIdx.x >> 5;
  int c0 = blockIdx.x * 32, r0 = blockIdx.y * 32;
  #pragma unroll
  for (int i = 0; i < 4; i++)
    t[ty + i*8][tx] = in[(size_t)(r0 + ty + i*8) * C + (c0 + tx)];
  __syncthreads();
  #pragma unroll
  for (int i = 0; i < 4; i++)
    out[(size_t)(c0 + ty + i*8) * R + (r0 + tx)] = f2bf(t[tx][ty + i*8]);
}

// ---------------- 128x128 bf16 GEMM core ----------------
template<int KDIM>
__device__ __forceinline__ void gemm_core(
    const u16* __restrict__ A, const u16* __restrict__ BT,
    int mt, int nt, f32x4 acc[4][4], u16* As, u16* Bs)
{
  int tid = threadIdx.x, lane = tid & 63, w = tid >> 6;
  int g = lane >> 4, c4 = lane & 15;
  int wr = w >> 1, wc = w & 1;
  int srow = lane >> 2;
  int pslot = (lane & 3) ^ ((lane >> 3) & 3);
  int rsel = g ^ ((c4 >> 1) & 3);
  const size_t abase = (size_t)(mt * 128) * KDIM;
  const size_t bbase = (size_t)(nt * 128) * KDIM;
  for (int kt = 0; kt < KDIM / 32; kt++) {
    __syncthreads();
    #pragma unroll
    for (int cc = 0; cc < 2; cc++) {
      int cid = w * 2 + cc;
      int row = cid * 16 + srow;
      GLOAD16(A + abase + (size_t)row * KDIM + kt * 32 + pslot * 8, As + cid * 512);
      GLOAD16(BT + bbase + (size_t)row * KDIM + kt * 32 + pslot * 8, Bs + cid * 512);
    }
    __syncthreads();
    bf16x8 af[4], bfv[4];
    #pragma unroll
    for (int f = 0; f < 4; f++) {
      af[f]  = *(const bf16x8*)(As + (wr * 64 + f * 16 + c4) * 32 + rsel * 8);
      bfv[f] = *(const bf16x8*)(Bs + (wc * 64 + f * 16 + c4) * 32 + rsel * 8);
    }
    #pragma unroll
    for (int fr = 0; fr < 4; fr++)
      #pragma unroll
      for (int fc = 0; fc < 4; fc++)
        acc[fr][fc] = MFMA16(af[fr], bfv[fc], acc[fr][fc]);
  }
}

// ---------------- K1: QKV projection GEMM ----------------
__global__ __launch_bounds__(256, 3) void k_qkv_gemm(
    const u16* __restrict__ A, const u16* __restrict__ BT, const float* __restrict__ bias,
    u16* __restrict__ qo, u16* __restrict__ ko, u16* __restrict__ vo)
{
  __shared__ u16 As[128 * 32], Bs[128 * 32];
  int bid0 = blockIdx.x;
  int bid = (bid0 & 7) * 441 + (bid0 >> 3);   // XCD-chunked swizzle (3528 = 8*441)
  int nt = bid % 18, mt = bid / 18;
  f32x4 z = {0.f, 0.f, 0.f, 0.f};
  f32x4 acc[4][4];
  #pragma unroll
  for (int i = 0; i < 4; i++)
    #pragma unroll
    for (int j = 0; j < 4; j++) acc[i][j] = z;
  gemm_core<768>(A, BT, mt, nt, acc, As, Bs);

  int tid = threadIdx.x, lane = tid & 63, w = tid >> 6;
  int g = lane >> 4, c4 = lane & 15;
  int wr = w >> 1, wc = w & 1;

  u16* dstA[4]; int ccA[4]; float bsA[4]; int hbA[4];
  #pragma unroll
  for (int fc = 0; fc < 4; fc++) {
    int n0 = nt * 128 + wc * 64 + fc * 16;
    int i3 = n0 / 768;
    int r = n0 - i3 * 768;
    dstA[fc] = (i3 == 0) ? qo : (i3 == 1) ? ko : vo;
    hbA[fc] = (r >> 6) * 128;
    ccA[fc] = (r & 63) + c4;
    bsA[fc] = bias[n0 + c4];
  }
  #pragma unroll
  for (int fr = 0; fr < 4; fr++) {
    #pragma unroll
    for (int j = 0; j < 4; j++) {
      int m = mt * 128 + wr * 64 + fr * 16 + g * 4 + j;
      int bb = m / 196;
      int ll = m - bb * 196;
      #pragma unroll
      for (int fc = 0; fc < 4; fc++) {
        dstA[fc][(size_t)((hbA[fc] + bb) * 196 + ll) * 64 + ccA[fc]] =
            f2bf(acc[fr][fc][j] + bsA[fc]);
      }
    }
  }
}

// ---------------- K3: output projection GEMM ----------------
__global__ __launch_bounds__(256, 3) void k_proj_gemm(
    const u16* __restrict__ A, const u16* __restrict__ BT, const float* __restrict__ bias,
    float* __restrict__ out)
{
  __shared__ u16 As[128 * 32], Bs[128 * 32];
  int bid0 = blockIdx.x;
  int bid = (bid0 & 7) * 147 + (bid0 >> 3);   // XCD-chunked swizzle (1176 = 8*147)
  int nt = bid % 6, mt = bid / 6;
  f32x4 z = {0.f, 0.f, 0.f, 0.f};
  f32x4 acc[4][4];
  #pragma unroll
  for (int i = 0; i < 4; i++)
    #pragma unroll
    for (int j = 0; j < 4; j++) acc[i][j] = z;
  gemm_core<768>(A, BT, mt, nt, acc, As, Bs);

  int tid = threadIdx.x, lane = tid & 63, w = tid >> 6;
  int g = lane >> 4, c4 = lane & 15;
  int wr = w >> 1, wc = w & 1;
  #pragma unroll
  for (int fc = 0; fc < 4; fc++) {
    int n0 = nt * 128 + wc * 64 + fc * 16 + c4;
    float bs = bias[n0];
    #pragma unroll
    for (int fr = 0; fr < 4; fr++)
      #pragma unroll
      for (int j = 0; j < 4; j++) {
        int m = mt * 128 + wr * 64 + fr * 16 + g * 4 + j;
        out[(size_t)m * 768 + n0] = acc[fr][fc][j] + bs;
      }
  }
}

// ---------------- K2: fused attention (S^T orientation, rel-pos fused into MFMA) ----------------
// One block (4 waves) per (head, batch). LDS:
//   K64 [208][64]  slot-XOR swizzled, pre-scaled by 1/8       26,624 B
//   Krel[208][40]  one-hot(kh)|one-hot(kw)|mask, stride-5 odd 16,640 B
//   VT  [64][232]  V^T with pair-permuted cols for PV A-frags 29,696 B
//   Qrel[4][16][40] per-wave: Fh|Fw|(-30000) built per q-tile  5,120 B  => 78,080 B, 2 blk/CU
// Per q-tile: 8 E-MFMAs -> scatter Qrel; 13x3 QK MFMAs (K64x2 + Krel);
// single-pass softmax in-register; PV via cvt_pk-packed B-frags (no P LDS, no shuffles).
__global__ __launch_bounds__(256, 2) void k_attn(
    const u16* __restrict__ Q, const u16* __restrict__ Kg, const u16* __restrict__ Vg,
    const u16* __restrict__ RPH, const u16* __restrict__ RPW, u16* __restrict__ Ows)
{
  __shared__ u16 K64[208 * 64];
  __shared__ u16 Krel[208 * 40];
  __shared__ u16 VT[64 * 232];
  __shared__ u16 Qrel[4][16 * 40];

  int bh = blockIdx.x;
  int hh = bh >> 7, bb = bh & 127;
  int tid = threadIdx.x, lane = tid & 63, w = tid >> 6;
  int g = lane >> 4, c4 = lane & 15;

  const u16* kbase = Kg + (size_t)bh * 12544;
  const u16* vbase = Vg + (size_t)bh * 12544;
  const u16* qbase = Q + (size_t)bh * 12544;

  // --- stage K64: scale by 1/8 (exact), slot-XOR swizzle ---
  for (int ch = tid; ch < 1664; ch += 256) {
    int row = ch >> 3, s = ch & 7;
    u16 outv[8];
    if (row < 196) {
      u16x8 v = *(const u16x8*)(kbase + row * 64 + s * 8);
      #pragma unroll
      for (int e = 0; e < 8; e++)
        outv[e] = f2bf(bits2f((uint32_t)v[e] << 16) * 0.125f);
    } else {
      #pragma unroll
      for (int e = 0; e < 8; e++) outv[e] = 0;
    }
    *(int4*)(K64 + row * 64 + ((s ^ (row & 7)) * 8)) = pack8(outv);
  }

  // --- stage Krel: one-hot rows ---
  if (tid < 208) {
    int k = tid;
    int kh = k / 14, kw2 = k - kh * 14;
    #pragma unroll
    for (int s = 0; s < 5; s++) {
      u16 vals[8];
      #pragma unroll
      for (int e = 0; e < 8; e++) {
        int c = s * 8 + e;
        u16 x = 0;
        if (k < 196) {
          if (c == kh) x = 0x3F80;
          else if (c == 14 + kw2) x = 0x3F80;
        } else {
          if (c == 28) x = 0x3F80;   // mask one-hot (pairs with Qrel[28] = -30000)
        }
        vals[e] = x;
      }
      *(int4*)(Krel + k * 40 + s * 8) = pack8(vals);
    }
  }

  // --- zero VT pad columns (keys 196..223 in permuted space) ---
  for (int i = tid; i < 2048; i += 256) {
    int chn = i >> 5, c = 192 + (i & 31);
    if (c >= 196) VT[chn * 232 + c] = 0;
  }
  // --- stage VT: transpose with pair-permuted columns ---
  // col'(key): pair = key>>5; kk = key&31; idx = kk&15; tile = kk>>4;
  //            col' = pair*32 + (idx>>2)*8 + (idx&3) + 4*tile
  for (int ch2 = tid; ch2 < 784; ch2 += 256) {
    int kp = ch2 >> 3, cb = ch2 & 7;
    int key = kp * 2, cz = cb * 8;
    u16x8 a = *(const u16x8*)(vbase + key * 64 + cz);
    u16x8 b2 = *(const u16x8*)(vbase + (key + 1) * 64 + cz);
    int kk = key & 31;
    int colp = (key >> 5) * 32 + ((kk & 15) >> 2) * 8 + (kk & 3) + ((kk >> 4) << 2);
    #pragma unroll
    for (int j = 0; j < 8; j++) {
      uint32_t pk = (uint32_t)a[j] | ((uint32_t)b2[j] << 16);
      *(uint32_t*)(VT + (cz + j) * 232 + colp) = pk;
    }
  }
  __syncthreads();

  // rel-pos table fragments (A-operands for E = R . Q^T), held in regs per block
  int t1 = 16 + c4; if (t1 > 26) t1 = 26;
  bf16x8 rh00 = *(const bf16x8*)(RPH + c4 * 64 + g * 8);
  bf16x8 rh01 = *(const bf16x8*)(RPH + c4 * 64 + 32 + g * 8);
  bf16x8 rh10 = *(const bf16x8*)(RPH + t1 * 64 + g * 8);
  bf16x8 rh11 = *(const bf16x8*)(RPH + t1 * 64 + 32 + g * 8);
  bf16x8 rw00 = *(const bf16x8*)(RPW + c4 * 64 + g * 8);
  bf16x8 rw01 = *(const bf16x8*)(RPW + c4 * 64 + 32 + g * 8);
  bf16x8 rw10 = *(const bf16x8*)(RPW + t1 * 64 + g * 8);
  bf16x8 rw11 = *(const bf16x8*)(RPW + t1 * 64 + 32 + g * 8);

  f32x4 z4 = {0.f, 0.f, 0.f, 0.f};

  for (int qt = w; qt < 13; qt += 4) {
    int qi = qt * 16 + c4;                 // this lane's q-row (S^T orientation)
    int qrow = qi > 195 ? 195 : qi;
    bf16x8 qa0 = *(const bf16x8*)(qbase + qrow * 64 + g * 8);
    bf16x8 qa1 = *(const bf16x8*)(qbase + qrow * 64 + 32 + g * 8);

    u16* Qr = (u16*)Qrel[w];
    {
      int4 zz = {0, 0, 0, 0};
      *(int4*)(Qr + lane * 8) = zz;
      if (lane < 16) *(int4*)(Qr + 512 + lane * 8) = zz;
      if (g == 0) Qr[c4 * 40 + 28] = f2bf(-30000.f);
    }

    int qh = qi / 14;
    int qwv = qi - qh * 14;

    // E^T = R . Q^T ; lane holds E[q=c4][t = tt*16 + 4g + j] -> scatter into own Qrel row
    f32x4 e0 = MFMA16(rh00, qa0, z4); e0 = MFMA16(rh01, qa1, e0);
    f32x4 e1 = MFMA16(rh10, qa0, z4); e1 = MFMA16(rh11, qa1, e1);
    #pragma unroll
    for (int tt = 0; tt < 2; tt++) {
      f32x4 e = tt ? e1 : e0;
      #pragma unroll
      for (int j = 0; j < 4; j++) {
        int t = tt * 16 + 4 * g + j;
        int kh = qh + 13 - t;
        if ((unsigned)kh <= 13u) Qr[c4 * 40 + kh] = f2bf(e[j]);
      }
    }
    f32x4 f0 = MFMA16(rw00, qa0, z4); f0 = MFMA16(rw01, qa1, f0);
    f32x4 f1 = MFMA16(rw10, qa0, z4); f1 = MFMA16(rw11, qa1, f1);
    #pragma unroll
    for (int tt = 0; tt < 2; tt++) {
      f32x4 e = tt ? f1 : f0;
      #pragma unroll
      for (int j = 0; j < 4; j++) {
        int t = tt * 16 + 4 * g + j;
        int kw3 = qwv + 13 - t;
        if ((unsigned)kw3 <= 13u) Qr[c4 * 40 + 14 + kw3] = f2bf(e[j]);
      }
    }

    bf16x8 qrelB = *(const bf16x8*)(Qr + c4 * 40 + g * 8);

    // S^T: St[i][j] = S[q=c4][key = 16i + 4g + j]
    f32x4 St[13];
    #pragma unroll
    for (int i = 0; i < 13; i++) {
      int key = i * 16 + c4;
      const u16* kr = K64 + key * 64;
      int sw = key & 7;
      bf16x8 kb0 = *(const bf16x8*)(kr + ((g ^ sw) * 8));
      bf16x8 kb1 = *(const bf16x8*)(kr + (((4 + g) ^ sw) * 8));
      f32x4 acc = MFMA16(kb0, qa0, z4);
      acc = MFMA16(kb1, qa1, acc);
      bf16x8 krl = *(const bf16x8*)(Krel + key * 40 + g * 8);
      St[i] = MFMA16(krl, qrelB, acc);
    }

    // single-pass softmax: row = lane's q, spread across g-groups
    float mx = -3.0e38f;
    #pragma unroll
    for (int i = 0; i < 13; i++)
      #pragma unroll
      for (int j = 0; j < 4; j++) mx = fmaxf(mx, St[i][j]);
    mx = fmaxf(mx, __shfl_xor(mx, 16));
    mx = fmaxf(mx, __shfl_xor(mx, 32));

    float ls = 0.f;
    f32x4 O[4] = {z4, z4, z4, z4};
    #pragma unroll
    for (int p = 0; p < 7; p++) {
      float pe[8];
      #pragma unroll
      for (int j2 = 0; j2 < 4; j2++) { pe[j2] = __expf(St[2 * p][j2] - mx); ls += pe[j2]; }
      if (p < 6) {
        #pragma unroll
        for (int j2 = 0; j2 < 4; j2++) { pe[4 + j2] = __expf(St[2 * p + 1][j2] - mx); ls += pe[4 + j2]; }
      } else {
        #pragma unroll
        for (int j2 = 0; j2 < 4; j2++) pe[4 + j2] = 0.f;
      }
      union { uint32_t u[4]; bf16x8 v; } pb;
      pb.u[0] = cvtpk(pe[0], pe[1]);
      pb.u[1] = cvtpk(pe[2], pe[3]);
      pb.u[2] = cvtpk(pe[4], pe[5]);
      pb.u[3] = cvtpk(pe[6], pe[7]);
      #pragma unroll
      for (int ct = 0; ct < 4; ct++) {
        bf16x8 va = *(const bf16x8*)(VT + (ct * 16 + c4) * 232 + p * 32 + g * 8);
        O[ct] = MFMA16(va, pb.v, O[ct]);   // O^T[ch][q] accumulates
      }
    }
    ls += __shfl_xor(ls, 16);
    ls += __shfl_xor(ls, 32);

    if (qi < 196) {
      float inv = 1.f / ls;
      size_t obase = (size_t)(bb * 196 + qi) * 768 + hh * 64;
      #pragma unroll
      for (int ct = 0; ct < 4; ct++) {
        uint32_t o0 = cvtpk(O[ct][0] * inv, O[ct][1] * inv);
        uint32_t o1 = cvtpk(O[ct][2] * inv, O[ct][3] * inv);
        uint2 ov = {o0, o1};
        *(uint2*)(Ows + obase + ct * 16 + g * 4) = ov;
      }
    }
  }
}

// ---------------- host launch ----------------
extern "C" void kernel_launch(void* const* d_in, const int* in_sizes, int n_in,
                              void* d_out, int out_size, void* d_ws, size_t ws_size,
                              hipStream_t stream) {
  (void)in_sizes; (void)n_in; (void)out_size; (void)ws_size;
  const float* x      = (const float*)d_in[0];
  const float* qkv_w  = (const float*)d_in[1];
  const float* qkv_b  = (const float*)d_in[2];
  const float* proj_w = (const float*)d_in[3];
  const float* proj_b = (const float*)d_in[4];
  const float* rph    = (const float*)d_in[5];
  const float* rpw    = (const float*)d_in[6];
  float* out = (float*)d_out;
  char* ws = (char*)d_ws;

  u16* xb   = (u16*)(ws);                 // 25088x768 bf16
  u16* wT   = (u16*)(ws + 38535168);      // 2304x768 bf16
  u16* pT   = (u16*)(ws + 42074112);      // 768x768 bf16
  u16* rphb = (u16*)(ws + 43253760);      // 27x64 bf16
  u16* rpwb = (u16*)(ws + 43257856);      // 27x64 bf16
  u16* qws  = (u16*)(ws + 43261952);      // 1536x196x64 bf16
  u16* kws  = (u16*)(ws + 81797120);
  u16* vws  = (u16*)(ws + 120332288);
  u16* Ows  = xb;                         // xb dead after K1

  k_cvt<<<2048, 256, 0, stream>>>(x, xb, 4816896);
  k_cvt<<<2, 256, 0, stream>>>(rph, rphb, 432);
  k_cvt<<<2, 256, 0, stream>>>(rpw, rpwb, 432);
  k_transpose<<<dim3(72, 24), 256, 0, stream>>>(qkv_w, wT, 768, 2304);
  k_transpose<<<dim3(24, 24), 256, 0, stream>>>(proj_w, pT, 768, 768);
  k_qkv_gemm<<<196 * 18, 256, 0, stream>>>(xb, wT, qkv_b, qws, kws, vws);
  k_attn<<<1536, 256, 0, stream>>>(qws, kws, vws, rphb, rpwb, Ows);
  k_proj_gemm<<<196 * 6, 256, 0, stream>>>(Ows, pT, proj_b, out);
}

// Round 3
// 275.173 us; speedup vs baseline: 1.1403x; 1.0005x over previous
//
#include <hip/hip_runtime.h>
#include <stdint.h>

typedef unsigned short u16;
typedef __bf16 bf16x8 __attribute__((ext_vector_type(8)));
typedef u16 u16x8 __attribute__((ext_vector_type(8)));
typedef float f32x4 __attribute__((ext_vector_type(4)));

#define MFMA16(a,b,c) __builtin_amdgcn_mfma_f32_16x16x32_bf16((a),(b),(c),0,0,0)
#define GLOAD16(gp, lp) __builtin_amdgcn_global_load_lds( \
    (const __attribute__((address_space(1))) void*)(gp), \
    (__attribute__((address_space(3))) void*)(lp), 16, 0, 0)

__device__ __forceinline__ u16 f2bf(float f) {
  union { float f; uint32_t u; } v; v.f = f;
  return (u16)((v.u + 0x7FFFu + ((v.u >> 16) & 1u)) >> 16);
}
__device__ __forceinline__ float bits2f(uint32_t u) {
  union { uint32_t u; float f; } v; v.u = u; return v.f;
}
__device__ __forceinline__ uint32_t cvtpk(float lo, float hi) {
  uint32_t r;
  asm("v_cvt_pk_bf16_f32 %0, %1, %2" : "=v"(r) : "v"(lo), "v"(hi));
  return r;
}
__device__ __forceinline__ int4 pack8(const u16* v) {
  int4 r;
  r.x = (int)((uint32_t)v[0] | ((uint32_t)v[1] << 16));
  r.y = (int)((uint32_t)v[2] | ((uint32_t)v[3] << 16));
  r.z = (int)((uint32_t)v[4] | ((uint32_t)v[5] << 16));
  r.w = (int)((uint32_t)v[6] | ((uint32_t)v[7] << 16));
  return r;
}

// ---------------- fp32 -> bf16 convert ----------------
__global__ void k_cvt(const float* __restrict__ in, u16* __restrict__ out, int n4) {
  int i = blockIdx.x * 256 + threadIdx.x;
  int stride = gridDim.x * 256;
  for (; i < n4; i += stride) {
    float4 v = reinterpret_cast<const float4*>(in)[i];
    ushort4 o;
    o.x = f2bf(v.x); o.y = f2bf(v.y); o.z = f2bf(v.z); o.w = f2bf(v.w);
    reinterpret_cast<ushort4*>(out)[i] = o;
  }
}

// ------------- fp32 (R x C) -> bf16 transposed (C x R) -------------
__global__ void k_transpose(const float* __restrict__ in, u16* __restrict__ out, int R, int C) {
  __shared__ float t[32][33];
  int tx = threadIdx.x & 31, ty = threadIdx.x >> 5;
  int c0 = blockIdx.x * 32, r0 = blockIdx.y * 32;
  #pragma unroll
  for (int i = 0; i < 4; i++)
    t[ty + i*8][tx] = in[(size_t)(r0 + ty + i*8) * C + (c0 + tx)];
  __syncthreads();
  #pragma unroll
  for (int i = 0; i < 4; i++)
    out[(size_t)(c0 + ty + i*8) * R + (r0 + tx)] = f2bf(t[tx][ty + i*8]);
}

// =========================================================================
// K1: 256x256 BK=32 pipelined QKV GEMM. 512 thr = 8 waves (2M x 4N).
// 4 K-tile LDS slots (A,B each 16KB/slot -> 128KB). Per phase:
// [ds_read frags][stage 1 unit (2x global_load_lds)][vmcnt(6)][s_barrier][16 MFMA].
// Stage of K-tile k+3 issues right after the barrier retiring K-tile k-1 -> race-free.
// LDS layout pair-packed + XOR swizzle: elem(row,kcol): pr=row>>1,b=row&1,g=kcol>>3:
//   byte = pr*128 + ((2g+b)^(pr&7))*16 + (kcol&7)*2   (2-way banks on all frag reads)
// =========================================================================
__global__ __launch_bounds__(512, 2) void k_qkv256(
    const u16* __restrict__ A, const u16* __restrict__ BT, const float* __restrict__ bias,
    u16* __restrict__ qo, u16* __restrict__ ko, u16* __restrict__ vo)
{
  __shared__ u16 SMEM[65536];   // A slots [0,32768), B slots [32768,65536)

  int bid0 = blockIdx.x;
  // bijective XCD swizzle for 882 = 8*110 + 2
  int xcd = bid0 & 7, idx = bid0 >> 3;
  int base = (xcd < 2) ? xcd * 111 : 2 * 111 + (xcd - 2) * 110;
  int wgid = base + idx;
  int mt = wgid / 9, nt = wgid - (wgid / 9) * 9;

  int tid = threadIdx.x, lane = tid & 63, w = tid >> 6;
  int g = lane >> 4, c4 = lane & 15;
  int wr = w >> 2, wc = w & 3;

  // staging chunk decode (constants per thread)
  int c1 = tid, c2 = tid + 512;
  int pr1 = c1 >> 3, sl1 = (c1 & 7) ^ (pr1 & 7);
  int g1 = sl1 >> 1, row1 = pr1 * 2 + (sl1 & 1);
  int pr2 = c2 >> 3, sl2 = (c2 & 7) ^ (pr2 & 7);
  int g2 = sl2 >> 1, row2 = pr2 * 2 + (sl2 & 1);

  const u16* pA1 = A + (size_t)(mt * 256 + row1) * 768 + g1 * 8;
  const u16* pA2 = A + (size_t)(mt * 256 + row2) * 768 + g2 * 8;
  const u16* pB1 = BT + (size_t)(nt * 256 + row1) * 768 + g1 * 8;
  const u16* pB2 = BT + (size_t)(nt * 256 + row2) * 768 + g2 * 8;

  // fragment read offsets (u16 units)
  int prc = c4 >> 1;
  int slotRd = (2 * g + (c4 & 1)) ^ prc;
  int aoff = wr * 4096 + prc * 64 + slotRd * 8;
  int boff = wc * 2048 + prc * 64 + slotRd * 8;

  f32x4 acc[8][4];
  f32x4 z4 = {0.f, 0.f, 0.f, 0.f};
  #pragma unroll
  for (int f = 0; f < 8; f++)
    #pragma unroll
    for (int fc = 0; fc < 4; fc++) acc[f][fc] = z4;

  // prologue: stage K-tiles 0,1,2 (A,B each)
  #pragma unroll
  for (int kk = 0; kk < 3; kk++) {
    u16* dA = SMEM + (kk << 13);
    GLOAD16(pA1 + kk * 32, dA + c1 * 8);
    GLOAD16(pA2 + kk * 32, dA + c2 * 8);
    u16* dB = SMEM + 32768 + (kk << 13);
    GLOAD16(pB1 + kk * 32, dB + c1 * 8);
    GLOAD16(pB2 + kk * 32, dB + c2 * 8);
  }
  asm volatile("s_waitcnt vmcnt(8)" ::: "memory");
  __builtin_amdgcn_s_barrier();

  for (int k = 0; k < 24; ++k) {
    const u16* As = SMEM + ((k & 3) << 13);
    const u16* Bs = SMEM + 32768 + ((k & 3) << 13);
    bf16x8 bfr[4], afr[4];
    #pragma unroll
    for (int fc = 0; fc < 4; fc++) bfr[fc] = *(const bf16x8*)(Bs + boff + fc * 512);
    #pragma unroll
    for (int f = 0; f < 4; f++) afr[f] = *(const bf16x8*)(As + aoff + f * 512);
    if (k < 21) {
      u16* d = SMEM + (((k + 3) & 3) << 13);
      GLOAD16(pA1 + (k + 3) * 32, d + c1 * 8);
      GLOAD16(pA2 + (k + 3) * 32, d + c2 * 8);
      asm volatile("s_waitcnt vmcnt(6)" ::: "memory");
    } else if (k == 21) {
      asm volatile("s_waitcnt vmcnt(0)" ::: "memory");
    }
    __builtin_amdgcn_s_barrier();
    #pragma unroll
    for (int f = 0; f < 4; f++)
      #pragma unroll
      for (int fc = 0; fc < 4; fc++)
        acc[f][fc] = MFMA16(afr[f], bfr[fc], acc[f][fc]);

    #pragma unroll
    for (int f = 0; f < 4; f++) afr[f] = *(const bf16x8*)(As + aoff + (4 + f) * 512);
    if (k < 21) {
      u16* d = SMEM + 32768 + (((k + 3) & 3) << 13);
      GLOAD16(pB1 + (k + 3) * 32, d + c1 * 8);
      GLOAD16(pB2 + (k + 3) * 32, d + c2 * 8);
      asm volatile("s_waitcnt vmcnt(6)" ::: "memory");
    }
    __builtin_amdgcn_s_barrier();
    #pragma unroll
    for (int f = 0; f < 4; f++)
      #pragma unroll
      for (int fc = 0; fc < 4; fc++)
        acc[4 + f][fc] = MFMA16(afr[f], bfr[fc], acc[4 + f][fc]);
  }

  // epilogue: bounce through LDS (per-wave 16KB), coalesced 16B stores
  __builtin_amdgcn_s_barrier();
  u16* Ob = SMEM + w * 8192;

  int i3 = nt / 3;
  u16* dst = (i3 == 0) ? qo : (i3 == 1) ? ko : vo;
  int head = (nt - i3 * 3) * 4 + wc;
  float bsv[4];
  #pragma unroll
  for (int fc = 0; fc < 4; fc++) bsv[fc] = bias[nt * 256 + wc * 64 + fc * 16 + c4];

  #pragma unroll
  for (int f = 0; f < 8; f++)
    #pragma unroll
    for (int fc = 0; fc < 4; fc++)
      #pragma unroll
      for (int j = 0; j < 4; j++)
        Ob[(f * 16 + 4 * g + j) * 64 + fc * 16 + c4] = f2bf(acc[f][fc][j] + bsv[fc]);

  int m0 = mt * 256 + wr * 128;
  #pragma unroll
  for (int it2 = 0; it2 < 16; ++it2) {
    int cc = it2 * 64 + lane;
    int row = cc >> 3, kc = cc & 7;
    int mm = m0 + row;
    int bb2 = mm / 196, ll = mm - bb2 * 196;
    int4 v = *(const int4*)(Ob + row * 64 + kc * 8);
    *(int4*)(dst + ((size_t)((head * 128 + bb2) * 196 + ll)) * 64 + kc * 8) = v;
  }
}

// ---------------- 128x128 bf16 GEMM core (for proj) ----------------
template<int KDIM>
__device__ __forceinline__ void gemm_core(
    const u16* __restrict__ A, const u16* __restrict__ BT,
    int mt, int nt, f32x4 acc[4][4], u16* As, u16* Bs)
{
  int tid = threadIdx.x, lane = tid & 63, w = tid >> 6;
  int g = lane >> 4, c4 = lane & 15;
  int wr = w >> 1, wc = w & 1;
  int srow = lane >> 2;
  int pslot = (lane & 3) ^ ((lane >> 3) & 3);
  int rsel = g ^ ((c4 >> 1) & 3);
  const size_t abase = (size_t)(mt * 128) * KDIM;
  const size_t bbase = (size_t)(nt * 128) * KDIM;
  for (int kt = 0; kt < KDIM / 32; kt++) {
    __syncthreads();
    #pragma unroll
    for (int cc = 0; cc < 2; cc++) {
      int cid = w * 2 + cc;
      int row = cid * 16 + srow;
      GLOAD16(A + abase + (size_t)row * KDIM + kt * 32 + pslot * 8, As + cid * 512);
      GLOAD16(BT + bbase + (size_t)row * KDIM + kt * 32 + pslot * 8, Bs + cid * 512);
    }
    __syncthreads();
    bf16x8 af[4], bfv[4];
    #pragma unroll
    for (int f = 0; f < 4; f++) {
      af[f]  = *(const bf16x8*)(As + (wr * 64 + f * 16 + c4) * 32 + rsel * 8);
      bfv[f] = *(const bf16x8*)(Bs + (wc * 64 + f * 16 + c4) * 32 + rsel * 8);
    }
    #pragma unroll
    for (int fr = 0; fr < 4; fr++)
      #pragma unroll
      for (int fc = 0; fc < 4; fc++)
        acc[fr][fc] = MFMA16(af[fr], bfv[fc], acc[fr][fc]);
  }
}

// ---------------- K3: output projection GEMM ----------------
__global__ __launch_bounds__(256, 3) void k_proj_gemm(
    const u16* __restrict__ A, const u16* __restrict__ BT, const float* __restrict__ bias,
    float* __restrict__ out)
{
  __shared__ u16 As[128 * 32], Bs[128 * 32];
  int bid0 = blockIdx.x;
  int bid = (bid0 & 7) * 147 + (bid0 >> 3);   // 1176 = 8*147
  int nt = bid % 6, mt = bid / 6;
  f32x4 z = {0.f, 0.f, 0.f, 0.f};
  f32x4 acc[4][4];
  #pragma unroll
  for (int i = 0; i < 4; i++)
    #pragma unroll
    for (int j = 0; j < 4; j++) acc[i][j] = z;
  gemm_core<768>(A, BT, mt, nt, acc, As, Bs);

  int tid = threadIdx.x, lane = tid & 63, w = tid >> 6;
  int g = lane >> 4, c4 = lane & 15;
  int wr = w >> 1, wc = w & 1;
  #pragma unroll
  for (int fc = 0; fc < 4; fc++) {
    int n0 = nt * 128 + wc * 64 + fc * 16 + c4;
    float bs = bias[n0];
    #pragma unroll
    for (int fr = 0; fr < 4; fr++)
      #pragma unroll
      for (int j = 0; j < 4; j++) {
        int m = mt * 128 + wr * 64 + fr * 16 + g * 4 + j;
        out[(size_t)m * 768 + n0] = acc[fr][fc][j] + bs;
      }
  }
}

// ---------------- K2: fused attention ----------------
#define VP 216
__global__ __launch_bounds__(256, 2) void k_attn(
    const u16* __restrict__ Q, const u16* __restrict__ Kg, const u16* __restrict__ Vg,
    const u16* __restrict__ RPH, const u16* __restrict__ RPW, u16* __restrict__ Ows)
{
  __shared__ u16 K64[208 * 64];
  __shared__ u16 Krel[208 * 40];
  __shared__ u16 VT[64 * VP];
  __shared__ u16 QO[4][1024];   // per-wave 16x64, row-XOR swizzled; Qrel + O bounce

  int bh = blockIdx.x;
  int hh = bh >> 7, bb = bh & 127;
  int tid = threadIdx.x, lane = tid & 63, w = tid >> 6;
  int g = lane >> 4, c4 = lane & 15;

  const u16* kbase = Kg + (size_t)bh * 12544;
  const u16* vbase = Vg + (size_t)bh * 12544;
  const u16* qbase = Q + (size_t)bh * 12544;

  // stage K64 (scaled by 1/8, slot-XOR)
  for (int ch = tid; ch < 1664; ch += 256) {
    int row = ch >> 3, s = ch & 7;
    u16 outv[8];
    if (row < 196) {
      u16x8 v = *(const u16x8*)(kbase + row * 64 + s * 8);
      #pragma unroll
      for (int e = 0; e < 8; e++)
        outv[e] = f2bf(bits2f((uint32_t)v[e] << 16) * 0.125f);
    } else {
      #pragma unroll
      for (int e = 0; e < 8; e++) outv[e] = 0;
    }
    *(int4*)(K64 + row * 64 + ((s ^ (row & 7)) * 8)) = pack8(outv);
  }
  // Krel one-hots
  if (tid < 208) {
    int k = tid;
    int kh = k / 14, kw2 = k - kh * 14;
    #pragma unroll
    for (int s = 0; s < 5; s++) {
      u16 vals[8];
      #pragma unroll
      for (int e = 0; e < 8; e++) {
        int c = s * 8 + e;
        u16 x = 0;
        if (k < 196) {
          if (c == kh) x = 0x3F80;
          else if (c == 14 + kw2) x = 0x3F80;
        } else {
          if (c == 28) x = 0x3F80;
        }
        vals[e] = x;
      }
      *(int4*)(Krel + k * 40 + s * 8) = pack8(vals);
    }
  }
  // VT zero pad cols 196..215
  for (int i = tid; i < 64 * 20; i += 256) {
    int chn = i / 20, col = 196 + (i - chn * 20);
    VT[chn * VP + col] = 0;
  }
  // VT stage (pair-permuted cols)
  for (int ch2 = tid; ch2 < 784; ch2 += 256) {
    int kp = ch2 >> 3, cb = ch2 & 7;
    int key = kp * 2, cz = cb * 8;
    u16x8 a = *(const u16x8*)(vbase + key * 64 + cz);
    u16x8 b2 = *(const u16x8*)(vbase + (key + 1) * 64 + cz);
    int kk = key & 31;
    int colp = (key >> 5) * 32 + ((kk & 15) >> 2) * 8 + (kk & 3) + ((kk >> 4) << 2);
    #pragma unroll
    for (int j = 0; j < 8; j++) {
      uint32_t pk = (uint32_t)a[j] | ((uint32_t)b2[j] << 16);
      *(uint32_t*)(VT + (cz + j) * VP + colp) = pk;
    }
  }
  __syncthreads();

  int t1 = 16 + c4; if (t1 > 26) t1 = 26;
  bf16x8 rh00 = *(const bf16x8*)(RPH + c4 * 64 + g * 8);
  bf16x8 rh01 = *(const bf16x8*)(RPH + c4 * 64 + 32 + g * 8);
  bf16x8 rh10 = *(const bf16x8*)(RPH + t1 * 64 + g * 8);
  bf16x8 rh11 = *(const bf16x8*)(RPH + t1 * 64 + 32 + g * 8);
  bf16x8 rw00 = *(const bf16x8*)(RPW + c4 * 64 + g * 8);
  bf16x8 rw01 = *(const bf16x8*)(RPW + c4 * 64 + 32 + g * 8);
  bf16x8 rw10 = *(const bf16x8*)(RPW + t1 * 64 + g * 8);
  bf16x8 rw11 = *(const bf16x8*)(RPW + t1 * 64 + 32 + g * 8);

  f32x4 z4 = {0.f, 0.f, 0.f, 0.f};
  int sw = c4 & 7;                     // row-swizzle for this lane's QO row (row = c4)

  for (int qt = w; qt < 13; qt += 4) {
    int qi = qt * 16 + c4;
    int qrow = qi > 195 ? 195 : qi;
    bf16x8 qa0 = *(const bf16x8*)(qbase + qrow * 64 + g * 8);
    bf16x8 qa1 = *(const bf16x8*)(qbase + qrow * 64 + 32 + g * 8);

    u16* Qr = (u16*)QO[w];
    {
      int4 zz = {0, 0, 0, 0};
      int zr = lane >> 2, zs = lane & 3;
      *(int4*)(Qr + zr * 64 + ((zs ^ (zr & 7)) * 8)) = zz;   // zero rows, cols 0..31
    }
    if (g == 0) Qr[c4 * 64 + (28 ^ (sw << 3))] = f2bf(-30000.f);

    int qh = qi / 14;
    int qwv = qi - qh * 14;

    f32x4 e0 = MFMA16(rh00, qa0, z4); e0 = MFMA16(rh01, qa1, e0);
    f32x4 e1 = MFMA16(rh10, qa0, z4); e1 = MFMA16(rh11, qa1, e1);
    #pragma unroll
    for (int tt = 0; tt < 2; tt++) {
      f32x4 e = tt ? e1 : e0;
      #pragma unroll
      for (int j = 0; j < 4; j++) {
        int t = tt * 16 + 4 * g + j;
        int kh = qh + 13 - t;
        if ((unsigned)kh <= 13u) Qr[c4 * 64 + (kh ^ (sw << 3))] = f2bf(e[j]);
      }
    }
    f32x4 f0 = MFMA16(rw00, qa0, z4); f0 = MFMA16(rw01, qa1, f0);
    f32x4 f1 = MFMA16(rw10, qa0, z4); f1 = MFMA16(rw11, qa1, f1);
    #pragma unroll
    for (int tt = 0; tt < 2; tt++) {
      f32x4 e = tt ? f1 : f0;
      #pragma unroll
      for (int j = 0; j < 4; j++) {
        int t = tt * 16 + 4 * g + j;
        int kw3 = qwv + 13 - t;
        if ((unsigned)kw3 <= 13u) Qr[c4 * 64 + ((14 + kw3) ^ (sw << 3))] = f2bf(e[j]);
      }
    }

    bf16x8 qrelB = *(const bf16x8*)(Qr + c4 * 64 + ((g ^ sw) * 8));

    f32x4 St[13];
    #pragma unroll
    for (int i = 0; i < 13; i++) {
      int key = i * 16 + c4;
      const u16* kr = K64 + key * 64;
      int swk = key & 7;
      bf16x8 kb0 = *(const bf16x8*)(kr + ((g ^ swk) * 8));
      bf16x8 kb1 = *(const bf16x8*)(kr + (((4 + g) ^ swk) * 8));
      f32x4 acc = MFMA16(kb0, qa0, z4);
      acc = MFMA16(kb1, qa1, acc);
      bf16x8 krl = *(const bf16x8*)(Krel + key * 40 + g * 8);
      St[i] = MFMA16(krl, qrelB, acc);
    }

    float mx = -3.0e38f;
    #pragma unroll
    for (int i = 0; i < 13; i++)
      #pragma unroll
      for (int j = 0; j < 4; j++) mx = fmaxf(mx, St[i][j]);
    mx = fmaxf(mx, __shfl_xor(mx, 16));
    mx = fmaxf(mx, __shfl_xor(mx, 32));

    float ls = 0.f;
    f32x4 O[4] = {z4, z4, z4, z4};
    #pragma unroll
    for (int p = 0; p < 7; p++) {
      float pe[8];
      #pragma unroll
      for (int j2 = 0; j2 < 4; j2++) { pe[j2] = __expf(St[2 * p][j2] - mx); ls += pe[j2]; }
      if (p < 6) {
        #pragma unroll
        for (int j2 = 0; j2 < 4; j2++) { pe[4 + j2] = __expf(St[2 * p + 1][j2] - mx); ls += pe[4 + j2]; }
      } else {
        #pragma unroll
        for (int j2 = 0; j2 < 4; j2++) pe[4 + j2] = 0.f;
      }
      union { uint32_t u[4]; bf16x8 v; } pb;
      pb.u[0] = cvtpk(pe[0], pe[1]);
      pb.u[1] = cvtpk(pe[2], pe[3]);
      pb.u[2] = cvtpk(pe[4], pe[5]);
      pb.u[3] = cvtpk(pe[6], pe[7]);
      #pragma unroll
      for (int ct = 0; ct < 4; ct++) {
        bf16x8 va = *(const bf16x8*)(VT + (ct * 16 + c4) * VP + p * 32 + g * 8);
        O[ct] = MFMA16(va, pb.v, O[ct]);
      }
    }
    ls += __shfl_xor(ls, 16);
    ls += __shfl_xor(ls, 32);

    // O -> per-wave LDS bounce (swizzled), then coalesced 16B stores
    float inv = 1.f / ls;
    #pragma unroll
    for (int ct = 0; ct < 4; ct++) {
      uint32_t o0 = cvtpk(O[ct][0] * inv, O[ct][1] * inv);
      uint32_t o1 = cvtpk(O[ct][2] * inv, O[ct][3] * inv);
      uint2 ov = {o0, o1};
      *(uint2*)(Qr + c4 * 64 + ((ct * 16 + g * 4) ^ (sw << 3))) = ov;
    }
    #pragma unroll
    for (int it = 0; it < 2; ++it) {
      int cc = it * 64 + lane;
      int row = cc >> 3, kc = cc & 7;
      int q = qt * 16 + row;
      if (q < 196) {
        int4 v = *(const int4*)(Qr + row * 64 + ((kc ^ (row & 7)) * 8));
        *(int4*)(Ows + (size_t)(bb * 196 + q) * 768 + hh * 64 + kc * 8) = v;
      }
    }
  }
}

// ---------------- host launch ----------------
extern "C" void kernel_launch(void* const* d_in, const int* in_sizes, int n_in,
                              void* d_out, int out_size, void* d_ws, size_t ws_size,
                              hipStream_t stream) {
  (void)in_sizes; (void)n_in; (void)out_size; (void)ws_size;
  const float* x      = (const float*)d_in[0];
  const float* qkv_w  = (const float*)d_in[1];
  const float* qkv_b  = (const float*)d_in[2];
  const float* proj_w = (const float*)d_in[3];
  const float* proj_b = (const float*)d_in[4];
  const float* rph    = (const float*)d_in[5];
  const float* rpw    = (const float*)d_in[6];
  float* out = (float*)d_out;
  char* ws = (char*)d_ws;

  u16* xb   = (u16*)(ws);                 // 25088x768 bf16
  u16* wT   = (u16*)(ws + 38535168);      // 2304x768 bf16
  u16* pT   = (u16*)(ws + 42074112);      // 768x768 bf16
  u16* rphb = (u16*)(ws + 43253760);      // 27x64 bf16
  u16* rpwb = (u16*)(ws + 43257856);      // 27x64 bf16
  u16* qws  = (u16*)(ws + 43261952);      // 1536x196x64 bf16
  u16* kws  = (u16*)(ws + 81797120);
  u16* vws  = (u16*)(ws + 120332288);
  u16* Ows  = xb;                         // xb dead after K1

  k_cvt<<<2048, 256, 0, stream>>>(x, xb, 4816896);
  k_cvt<<<2, 256, 0, stream>>>(rph, rphb, 432);
  k_cvt<<<2, 256, 0, stream>>>(rpw, rpwb, 432);
  k_transpose<<<dim3(72, 24), 256, 0, stream>>>(qkv_w, wT, 768, 2304);
  k_transpose<<<dim3(24, 24), 256, 0, stream>>>(proj_w, pT, 768, 768);
  k_qkv256<<<882, 512, 0, stream>>>(xb, wT, qkv_b, qws, kws, vws);
  k_attn<<<1536, 256, 0, stream>>>(qws, kws, vws, rphb, rpwb, Ows);
  k_proj_gemm<<<196 * 6, 256, 0, stream>>>(Ows, pT, proj_b, out);
}

// Round 4
// 261.651 us; speedup vs baseline: 1.1992x; 1.0517x over previous
//
#include <hip/hip_runtime.h>
#include <stdint.h>

typedef unsigned short u16;
typedef __bf16 bf16x8 __attribute__((ext_vector_type(8)));
typedef u16 u16x8 __attribute__((ext_vector_type(8)));
typedef float f32x4 __attribute__((ext_vector_type(4)));

#define MFMA16(a,b,c) __builtin_amdgcn_mfma_f32_16x16x32_bf16((a),(b),(c),0,0,0)
#define GLOAD16(gp, lp) __builtin_amdgcn_global_load_lds( \
    (const __attribute__((address_space(1))) void*)(gp), \
    (__attribute__((address_space(3))) void*)(lp), 16, 0, 0)

__device__ __forceinline__ u16 f2bf(float f) {
  union { float f; uint32_t u; } v; v.f = f;
  return (u16)((v.u + 0x7FFFu + ((v.u >> 16) & 1u)) >> 16);
}
__device__ __forceinline__ float bits2f(uint32_t u) {
  union { uint32_t u; float f; } v; v.u = u; return v.f;
}
__device__ __forceinline__ uint32_t cvtpk(float lo, float hi) {
  uint32_t r;
  asm("v_cvt_pk_bf16_f32 %0, %1, %2" : "=v"(r) : "v"(lo), "v"(hi));
  return r;
}
__device__ __forceinline__ int4 pack8(const u16* v) {
  int4 r;
  r.x = (int)((uint32_t)v[0] | ((uint32_t)v[1] << 16));
  r.y = (int)((uint32_t)v[2] | ((uint32_t)v[3] << 16));
  r.z = (int)((uint32_t)v[4] | ((uint32_t)v[5] << 16));
  r.w = (int)((uint32_t)v[6] | ((uint32_t)v[7] << 16));
  return r;
}

// ---------------- fp32 -> bf16 convert ----------------
__global__ void k_cvt(const float* __restrict__ in, u16* __restrict__ out, int n4) {
  int i = blockIdx.x * 256 + threadIdx.x;
  int stride = gridDim.x * 256;
  for (; i < n4; i += stride) {
    float4 v = reinterpret_cast<const float4*>(in)[i];
    ushort4 o;
    o.x = f2bf(v.x); o.y = f2bf(v.y); o.z = f2bf(v.z); o.w = f2bf(v.w);
    reinterpret_cast<ushort4*>(out)[i] = o;
  }
}

// ------------- fp32 (R x C) -> bf16 transposed (C x R) -------------
__global__ void k_transpose(const float* __restrict__ in, u16* __restrict__ out, int R, int C) {
  __shared__ float t[32][33];
  int tx = threadIdx.x & 31, ty = threadIdx.x >> 5;
  int c0 = blockIdx.x * 32, r0 = blockIdx.y * 32;
  #pragma unroll
  for (int i = 0; i < 4; i++)
    t[ty + i*8][tx] = in[(size_t)(r0 + ty + i*8) * C + (c0 + tx)];
  __syncthreads();
  #pragma unroll
  for (int i = 0; i < 4; i++)
    out[(size_t)(c0 + ty + i*8) * R + (r0 + tx)] = f2bf(t[tx][ty + i*8]);
}

// =========================================================================
// K1: 256x256 BK=32 pipelined QKV GEMM. 512 thr = 8 waves (2M x 4N).
// 4 K-tile LDS slots. Per half-phase: [ds_read frags][stage 2 gload][vmcnt(6)]
// [barrier][setprio(1) 16 MFMA setprio(0)]. Direct scattered epilogue stores.
// =========================================================================
__global__ __launch_bounds__(512, 2) void k_qkv256(
    const u16* __restrict__ A, const u16* __restrict__ BT, const float* __restrict__ bias,
    u16* __restrict__ qo, u16* __restrict__ ko, u16* __restrict__ vo)
{
  __shared__ u16 SMEM[65536];   // A slots [0,32768), B slots [32768,65536)

  int bid0 = blockIdx.x;
  // bijective XCD swizzle for 882 = 8*110 + 2
  int xcd = bid0 & 7, idx = bid0 >> 3;
  int base = (xcd < 2) ? xcd * 111 : 2 * 111 + (xcd - 2) * 110;
  int wgid = base + idx;
  int mt = wgid / 9, nt = wgid - (wgid / 9) * 9;

  int tid = threadIdx.x, lane = tid & 63, w = tid >> 6;
  int g = lane >> 4, c4 = lane & 15;
  int wr = w >> 2, wc = w & 3;

  // staging chunk decode
  int c1 = tid, c2 = tid + 512;
  int pr1 = c1 >> 3, sl1 = (c1 & 7) ^ (pr1 & 7);
  int g1 = sl1 >> 1, row1 = pr1 * 2 + (sl1 & 1);
  int pr2 = c2 >> 3, sl2 = (c2 & 7) ^ (pr2 & 7);
  int g2 = sl2 >> 1, row2 = pr2 * 2 + (sl2 & 1);

  const u16* pA1 = A + (size_t)(mt * 256 + row1) * 768 + g1 * 8;
  const u16* pA2 = A + (size_t)(mt * 256 + row2) * 768 + g2 * 8;
  const u16* pB1 = BT + (size_t)(nt * 256 + row1) * 768 + g1 * 8;
  const u16* pB2 = BT + (size_t)(nt * 256 + row2) * 768 + g2 * 8;

  // fragment read offsets (u16 units)
  int prc = c4 >> 1;
  int slotRd = (2 * g + (c4 & 1)) ^ prc;
  int aoff = wr * 4096 + prc * 64 + slotRd * 8;
  int boff = wc * 2048 + prc * 64 + slotRd * 8;

  f32x4 acc[8][4];
  f32x4 z4 = {0.f, 0.f, 0.f, 0.f};
  #pragma unroll
  for (int f = 0; f < 8; f++)
    #pragma unroll
    for (int fc = 0; fc < 4; fc++) acc[f][fc] = z4;

  // prologue: stage K-tiles 0,1,2
  #pragma unroll
  for (int kk = 0; kk < 3; kk++) {
    u16* dA = SMEM + (kk << 13);
    GLOAD16(pA1 + kk * 32, dA + c1 * 8);
    GLOAD16(pA2 + kk * 32, dA + c2 * 8);
    u16* dB = SMEM + 32768 + (kk << 13);
    GLOAD16(pB1 + kk * 32, dB + c1 * 8);
    GLOAD16(pB2 + kk * 32, dB + c2 * 8);
  }
  asm volatile("s_waitcnt vmcnt(8)" ::: "memory");
  __builtin_amdgcn_s_barrier();

  for (int k = 0; k < 24; ++k) {
    const u16* As = SMEM + ((k & 3) << 13);
    const u16* Bs = SMEM + 32768 + ((k & 3) << 13);
    bf16x8 bfr[4], afr[4];
    #pragma unroll
    for (int fc = 0; fc < 4; fc++) bfr[fc] = *(const bf16x8*)(Bs + boff + fc * 512);
    #pragma unroll
    for (int f = 0; f < 4; f++) afr[f] = *(const bf16x8*)(As + aoff + f * 512);
    if (k < 21) {
      u16* d = SMEM + (((k + 3) & 3) << 13);
      GLOAD16(pA1 + (k + 3) * 32, d + c1 * 8);
      GLOAD16(pA2 + (k + 3) * 32, d + c2 * 8);
      asm volatile("s_waitcnt vmcnt(6)" ::: "memory");
    } else if (k == 21) {
      asm volatile("s_waitcnt vmcnt(0)" ::: "memory");
    }
    __builtin_amdgcn_s_barrier();
    __builtin_amdgcn_s_setprio(1);
    #pragma unroll
    for (int f = 0; f < 4; f++)
      #pragma unroll
      for (int fc = 0; fc < 4; fc++)
        acc[f][fc] = MFMA16(afr[f], bfr[fc], acc[f][fc]);
    __builtin_amdgcn_s_setprio(0);

    #pragma unroll
    for (int f = 0; f < 4; f++) afr[f] = *(const bf16x8*)(As + aoff + (4 + f) * 512);
    if (k < 21) {
      u16* d = SMEM + 32768 + (((k + 3) & 3) << 13);
      GLOAD16(pB1 + (k + 3) * 32, d + c1 * 8);
      GLOAD16(pB2 + (k + 3) * 32, d + c2 * 8);
      asm volatile("s_waitcnt vmcnt(6)" ::: "memory");
    }
    __builtin_amdgcn_s_barrier();
    __builtin_amdgcn_s_setprio(1);
    #pragma unroll
    for (int f = 0; f < 4; f++)
      #pragma unroll
      for (int fc = 0; fc < 4; fc++)
        acc[4 + f][fc] = MFMA16(afr[f], bfr[fc], acc[4 + f][fc]);
    __builtin_amdgcn_s_setprio(0);
  }

  // epilogue: direct scattered stores (R2-proven: 0 conflicts, ideal WRITE_SIZE)
  int i3 = nt / 3;
  u16* dst = (i3 == 0) ? qo : (i3 == 1) ? ko : vo;
  int head = (nt - i3 * 3) * 4 + wc;
  float bsv[4];
  #pragma unroll
  for (int fc = 0; fc < 4; fc++) bsv[fc] = bias[nt * 256 + wc * 64 + fc * 16 + c4];

  int mbase = mt * 256 + wr * 128 + g * 4;
  #pragma unroll
  for (int f = 0; f < 8; f++) {
    #pragma unroll
    for (int j = 0; j < 4; j++) {
      int mm = mbase + f * 16 + j;
      int bb2 = mm / 196, ll = mm - bb2 * 196;
      size_t ro = (size_t)((head * 128 + bb2) * 196 + ll) * 64;
      #pragma unroll
      for (int fc = 0; fc < 4; fc++)
        dst[ro + fc * 16 + c4] = f2bf(acc[f][fc][j] + bsv[fc]);
    }
  }
}

// =========================================================================
// K3: 128x128 BK=32 pipelined proj GEMM. 256 thr = 4 waves (2x2).
// Same 4-slot counted-vmcnt schedule; 64KB LDS -> 2 blocks/CU.
// =========================================================================
__global__ __launch_bounds__(256, 2) void k_proj256(
    const u16* __restrict__ A, const u16* __restrict__ BT, const float* __restrict__ bias,
    float* __restrict__ out)
{
  __shared__ u16 SMEM[32768];   // A slots [0,16384), B slots [16384,32768)

  int bid0 = blockIdx.x;
  int bid = (bid0 & 7) * 147 + (bid0 >> 3);   // 1176 = 8*147
  int nt = bid % 6, mt = bid / 6;

  int tid = threadIdx.x, lane = tid & 63, w = tid >> 6;
  int g = lane >> 4, c4 = lane & 15;
  int wr = w >> 1, wc = w & 1;

  int c1 = tid, c2 = tid + 256;
  int pr1 = c1 >> 3, sl1 = (c1 & 7) ^ (pr1 & 7);
  int g1 = sl1 >> 1, row1 = pr1 * 2 + (sl1 & 1);
  int pr2 = c2 >> 3, sl2 = (c2 & 7) ^ (pr2 & 7);
  int g2 = sl2 >> 1, row2 = pr2 * 2 + (sl2 & 1);

  const u16* pA1 = A + (size_t)(mt * 128 + row1) * 768 + g1 * 8;
  const u16* pA2 = A + (size_t)(mt * 128 + row2) * 768 + g2 * 8;
  const u16* pB1 = BT + (size_t)(nt * 128 + row1) * 768 + g1 * 8;
  const u16* pB2 = BT + (size_t)(nt * 128 + row2) * 768 + g2 * 8;

  int prc = c4 >> 1;
  int slotRd = (2 * g + (c4 & 1)) ^ prc;
  int aoff = wr * 2048 + prc * 64 + slotRd * 8;
  int boff = wc * 2048 + prc * 64 + slotRd * 8;

  f32x4 acc[4][4];
  f32x4 z4 = {0.f, 0.f, 0.f, 0.f};
  #pragma unroll
  for (int f = 0; f < 4; f++)
    #pragma unroll
    for (int fc = 0; fc < 4; fc++) acc[f][fc] = z4;

  #pragma unroll
  for (int kk = 0; kk < 3; kk++) {
    u16* dA = SMEM + (kk << 12);
    GLOAD16(pA1 + kk * 32, dA + c1 * 8);
    GLOAD16(pA2 + kk * 32, dA + c2 * 8);
    u16* dB = SMEM + 16384 + (kk << 12);
    GLOAD16(pB1 + kk * 32, dB + c1 * 8);
    GLOAD16(pB2 + kk * 32, dB + c2 * 8);
  }
  asm volatile("s_waitcnt vmcnt(8)" ::: "memory");
  __builtin_amdgcn_s_barrier();

  for (int k = 0; k < 24; ++k) {
    const u16* As = SMEM + ((k & 3) << 12);
    const u16* Bs = SMEM + 16384 + ((k & 3) << 12);
    bf16x8 bfr[4], afr[4];
    #pragma unroll
    for (int fc = 0; fc < 4; fc++) bfr[fc] = *(const bf16x8*)(Bs + boff + fc * 512);
    #pragma unroll
    for (int f = 0; f < 4; f++) afr[f] = *(const bf16x8*)(As + aoff + f * 512);
    if (k < 21) {
      u16* dA = SMEM + (((k + 3) & 3) << 12);
      GLOAD16(pA1 + (k + 3) * 32, dA + c1 * 8);
      GLOAD16(pA2 + (k + 3) * 32, dA + c2 * 8);
      u16* dB = SMEM + 16384 + (((k + 3) & 3) << 12);
      GLOAD16(pB1 + (k + 3) * 32, dB + c1 * 8);
      GLOAD16(pB2 + (k + 3) * 32, dB + c2 * 8);
      asm volatile("s_waitcnt vmcnt(8)" ::: "memory");
    } else if (k == 21) {
      asm volatile("s_waitcnt vmcnt(4)" ::: "memory");
    } else if (k == 22) {
      asm volatile("s_waitcnt vmcnt(0)" ::: "memory");
    }
    __builtin_amdgcn_s_barrier();
    __builtin_amdgcn_s_setprio(1);
    #pragma unroll
    for (int f = 0; f < 4; f++)
      #pragma unroll
      for (int fc = 0; fc < 4; fc++)
        acc[f][fc] = MFMA16(afr[f], bfr[fc], acc[f][fc]);
    __builtin_amdgcn_s_setprio(0);
    __builtin_amdgcn_s_barrier();
  }

  #pragma unroll
  for (int fc = 0; fc < 4; fc++) {
    int n0 = nt * 128 + wc * 64 + fc * 16 + c4;
    float bs = bias[n0];
    #pragma unroll
    for (int fr = 0; fr < 4; fr++)
      #pragma unroll
      for (int j = 0; j < 4; j++) {
        int m = mt * 128 + wr * 64 + fr * 16 + g * 4 + j;
        out[(size_t)m * 768 + n0] = acc[fr][fc][j] + bs;
      }
  }
}

// ---------------- K2: fused attention (R2 verbatim) ----------------
#define VP 232
__global__ __launch_bounds__(256, 2) void k_attn(
    const u16* __restrict__ Q, const u16* __restrict__ Kg, const u16* __restrict__ Vg,
    const u16* __restrict__ RPH, const u16* __restrict__ RPW, u16* __restrict__ Ows)
{
  __shared__ u16 K64[208 * 64];
  __shared__ u16 Krel[208 * 40];
  __shared__ u16 VT[64 * VP];
  __shared__ u16 Qrel[4][16 * 40];

  int bh = blockIdx.x;
  int hh = bh >> 7, bb = bh & 127;
  int tid = threadIdx.x, lane = tid & 63, w = tid >> 6;
  int g = lane >> 4, c4 = lane & 15;

  const u16* kbase = Kg + (size_t)bh * 12544;
  const u16* vbase = Vg + (size_t)bh * 12544;
  const u16* qbase = Q + (size_t)bh * 12544;

  // stage K64 (scaled by 1/8, slot-XOR)
  for (int ch = tid; ch < 1664; ch += 256) {
    int row = ch >> 3, s = ch & 7;
    u16 outv[8];
    if (row < 196) {
      u16x8 v = *(const u16x8*)(kbase + row * 64 + s * 8);
      #pragma unroll
      for (int e = 0; e < 8; e++)
        outv[e] = f2bf(bits2f((uint32_t)v[e] << 16) * 0.125f);
    } else {
      #pragma unroll
      for (int e = 0; e < 8; e++) outv[e] = 0;
    }
    *(int4*)(K64 + row * 64 + ((s ^ (row & 7)) * 8)) = pack8(outv);
  }
  // Krel one-hots
  if (tid < 208) {
    int k = tid;
    int kh = k / 14, kw2 = k - kh * 14;
    #pragma unroll
    for (int s = 0; s < 5; s++) {
      u16 vals[8];
      #pragma unroll
      for (int e = 0; e < 8; e++) {
        int c = s * 8 + e;
        u16 x = 0;
        if (k < 196) {
          if (c == kh) x = 0x3F80;
          else if (c == 14 + kw2) x = 0x3F80;
        } else {
          if (c == 28) x = 0x3F80;
        }
        vals[e] = x;
      }
      *(int4*)(Krel + k * 40 + s * 8) = pack8(vals);
    }
  }
  // VT zero pad cols
  for (int i = tid; i < 2048; i += 256) {
    int chn = i >> 5, c = 192 + (i & 31);
    if (c >= 196 && c < VP) VT[chn * VP + c] = 0;
  }
  // VT stage (pair-permuted cols)
  for (int ch2 = tid; ch2 < 784; ch2 += 256) {
    int kp = ch2 >> 3, cb = ch2 & 7;
    int key = kp * 2, cz = cb * 8;
    u16x8 a = *(const u16x8*)(vbase + key * 64 + cz);
    u16x8 b2 = *(const u16x8*)(vbase + (key + 1) * 64 + cz);
    int kk = key & 31;
    int colp = (key >> 5) * 32 + ((kk & 15) >> 2) * 8 + (kk & 3) + ((kk >> 4) << 2);
    #pragma unroll
    for (int j = 0; j < 8; j++) {
      uint32_t pk = (uint32_t)a[j] | ((uint32_t)b2[j] << 16);
      *(uint32_t*)(VT + (cz + j) * VP + colp) = pk;
    }
  }
  __syncthreads();

  int t1 = 16 + c4; if (t1 > 26) t1 = 26;
  bf16x8 rh00 = *(const bf16x8*)(RPH + c4 * 64 + g * 8);
  bf16x8 rh01 = *(const bf16x8*)(RPH + c4 * 64 + 32 + g * 8);
  bf16x8 rh10 = *(const bf16x8*)(RPH + t1 * 64 + g * 8);
  bf16x8 rh11 = *(const bf16x8*)(RPH + t1 * 64 + 32 + g * 8);
  bf16x8 rw00 = *(const bf16x8*)(RPW + c4 * 64 + g * 8);
  bf16x8 rw01 = *(const bf16x8*)(RPW + c4 * 64 + 32 + g * 8);
  bf16x8 rw10 = *(const bf16x8*)(RPW + t1 * 64 + g * 8);
  bf16x8 rw11 = *(const bf16x8*)(RPW + t1 * 64 + 32 + g * 8);

  f32x4 z4 = {0.f, 0.f, 0.f, 0.f};

  for (int qt = w; qt < 13; qt += 4) {
    int qi = qt * 16 + c4;
    int qrow = qi > 195 ? 195 : qi;
    bf16x8 qa0 = *(const bf16x8*)(qbase + qrow * 64 + g * 8);
    bf16x8 qa1 = *(const bf16x8*)(qbase + qrow * 64 + 32 + g * 8);

    u16* Qr = (u16*)Qrel[w];
    {
      int4 zz = {0, 0, 0, 0};
      *(int4*)(Qr + lane * 8) = zz;
      if (lane < 16) *(int4*)(Qr + 512 + lane * 8) = zz;
      if (g == 0) Qr[c4 * 40 + 28] = f2bf(-30000.f);
    }

    int qh = qi / 14;
    int qwv = qi - qh * 14;

    f32x4 e0 = MFMA16(rh00, qa0, z4); e0 = MFMA16(rh01, qa1, e0);
    f32x4 e1 = MFMA16(rh10, qa0, z4); e1 = MFMA16(rh11, qa1, e1);
    #pragma unroll
    for (int tt = 0; tt < 2; tt++) {
      f32x4 e = tt ? e1 : e0;
      #pragma unroll
      for (int j = 0; j < 4; j++) {
        int t = tt * 16 + 4 * g + j;
        int kh = qh + 13 - t;
        if ((unsigned)kh <= 13u) Qr[c4 * 40 + kh] = f2bf(e[j]);
      }
    }
    f32x4 f0 = MFMA16(rw00, qa0, z4); f0 = MFMA16(rw01, qa1, f0);
    f32x4 f1 = MFMA16(rw10, qa0, z4); f1 = MFMA16(rw11, qa1, f1);
    #pragma unroll
    for (int tt = 0; tt < 2; tt++) {
      f32x4 e = tt ? f1 : f0;
      #pragma unroll
      for (int j = 0; j < 4; j++) {
        int t = tt * 16 + 4 * g + j;
        int kw3 = qwv + 13 - t;
        if ((unsigned)kw3 <= 13u) Qr[c4 * 40 + 14 + kw3] = f2bf(e[j]);
      }
    }

    bf16x8 qrelB = *(const bf16x8*)(Qr + c4 * 40 + g * 8);

    f32x4 St[13];
    #pragma unroll
    for (int i = 0; i < 13; i++) {
      int key = i * 16 + c4;
      const u16* kr = K64 + key * 64;
      int sw = key & 7;
      bf16x8 kb0 = *(const bf16x8*)(kr + ((g ^ sw) * 8));
      bf16x8 kb1 = *(const bf16x8*)(kr + (((4 + g) ^ sw) * 8));
      f32x4 acc = MFMA16(kb0, qa0, z4);
      acc = MFMA16(kb1, qa1, acc);
      bf16x8 krl = *(const bf16x8*)(Krel + key * 40 + g * 8);
      St[i] = MFMA16(krl, qrelB, acc);
    }

    float mx = -3.0e38f;
    #pragma unroll
    for (int i = 0; i < 13; i++)
      #pragma unroll
      for (int j = 0; j < 4; j++) mx = fmaxf(mx, St[i][j]);
    mx = fmaxf(mx, __shfl_xor(mx, 16));
    mx = fmaxf(mx, __shfl_xor(mx, 32));

    float ls = 0.f;
    f32x4 O[4] = {z4, z4, z4, z4};
    #pragma unroll
    for (int p = 0; p < 7; p++) {
      float pe[8];
      #pragma unroll
      for (int j2 = 0; j2 < 4; j2++) { pe[j2] = __expf(St[2 * p][j2] - mx); ls += pe[j2]; }
      if (p < 6) {
        #pragma unroll
        for (int j2 = 0; j2 < 4; j2++) { pe[4 + j2] = __expf(St[2 * p + 1][j2] - mx); ls += pe[4 + j2]; }
      } else {
        #pragma unroll
        for (int j2 = 0; j2 < 4; j2++) pe[4 + j2] = 0.f;
      }
      union { uint32_t u[4]; bf16x8 v; } pb;
      pb.u[0] = cvtpk(pe[0], pe[1]);
      pb.u[1] = cvtpk(pe[2], pe[3]);
      pb.u[2] = cvtpk(pe[4], pe[5]);
      pb.u[3] = cvtpk(pe[6], pe[7]);
      #pragma unroll
      for (int ct = 0; ct < 4; ct++) {
        bf16x8 va = *(const bf16x8*)(VT + (ct * 16 + c4) * VP + p * 32 + g * 8);
        O[ct] = MFMA16(va, pb.v, O[ct]);
      }
    }
    ls += __shfl_xor(ls, 16);
    ls += __shfl_xor(ls, 32);

    if (qi < 196) {
      float inv = 1.f / ls;
      size_t obase = (size_t)(bb * 196 + qi) * 768 + hh * 64;
      #pragma unroll
      for (int ct = 0; ct < 4; ct++) {
        uint32_t o0 = cvtpk(O[ct][0] * inv, O[ct][1] * inv);
        uint32_t o1 = cvtpk(O[ct][2] * inv, O[ct][3] * inv);
        uint2 ov = {o0, o1};
        *(uint2*)(Ows + obase + ct * 16 + g * 4) = ov;
      }
    }
  }
}

// ---------------- host launch ----------------
extern "C" void kernel_launch(void* const* d_in, const int* in_sizes, int n_in,
                              void* d_out, int out_size, void* d_ws, size_t ws_size,
                              hipStream_t stream) {
  (void)in_sizes; (void)n_in; (void)out_size; (void)ws_size;
  const float* x      = (const float*)d_in[0];
  const float* qkv_w  = (const float*)d_in[1];
  const float* qkv_b  = (const float*)d_in[2];
  const float* proj_w = (const float*)d_in[3];
  const float* proj_b = (const float*)d_in[4];
  const float* rph    = (const float*)d_in[5];
  const float* rpw    = (const float*)d_in[6];
  float* out = (float*)d_out;
  char* ws = (char*)d_ws;

  u16* xb   = (u16*)(ws);                 // 25088x768 bf16
  u16* wT   = (u16*)(ws + 38535168);      // 2304x768 bf16
  u16* pT   = (u16*)(ws + 42074112);      // 768x768 bf16
  u16* rphb = (u16*)(ws + 43253760);      // 27x64 bf16
  u16* rpwb = (u16*)(ws + 43257856);      // 27x64 bf16
  u16* qws  = (u16*)(ws + 43261952);      // 1536x196x64 bf16
  u16* kws  = (u16*)(ws + 81797120);
  u16* vws  = (u16*)(ws + 120332288);
  u16* Ows  = xb;                         // xb dead after K1

  k_cvt<<<2048, 256, 0, stream>>>(x, xb, 4816896);
  k_cvt<<<2, 256, 0, stream>>>(rph, rphb, 432);
  k_cvt<<<2, 256, 0, stream>>>(rpw, rpwb, 432);
  k_transpose<<<dim3(72, 24), 256, 0, stream>>>(qkv_w, wT, 768, 2304);
  k_transpose<<<dim3(24, 24), 256, 0, stream>>>(proj_w, pT, 768, 768);
  k_qkv256<<<882, 512, 0, stream>>>(xb, wT, qkv_b, qws, kws, vws);
  k_attn<<<1536, 256, 0, stream>>>(qws, kws, vws, rphb, rpwb, Ows);
  k_proj256<<<1176, 256, 0, stream>>>(Ows, pT, proj_b, out);
}